// Round 1
// baseline (987.820 us; speedup 1.0000x reference)
//
#include <hip/hip_runtime.h>

#define LEAKY(v) ((v) >= 0.0f ? (v) : 0.2f * (v))

// ---------------- CSR build ----------------

__global__ __launch_bounds__(256) void count_deg(const int* ei, int* deg, int E, int Etot) {
    int i = blockIdx.x * 256 + threadIdx.x;
    if (i >= Etot) return;
    int d = (i < E) ? ei[E + i] : (i - E);   // self-loops appended
    atomicAdd(&deg[d], 1);
}

__global__ __launch_bounds__(512) void scan_block(const int* deg, int* excl, int* bsum, int n) {
    __shared__ int s[512];
    int t = threadIdx.x;
    int i = blockIdx.x * 512 + t;
    int v = (i < n) ? deg[i] : 0;
    s[t] = v;
    __syncthreads();
    for (int d = 1; d < 512; d <<= 1) {
        int x = 0;
        if (t >= d) x = s[t - d];
        __syncthreads();
        if (t >= d) s[t] += x;
        __syncthreads();
    }
    if (i < n) excl[i] = s[t] - v;          // exclusive within block
    if (t == 511) bsum[blockIdx.x] = s[511];
}

__global__ __launch_bounds__(512) void scan_sums(const int* bsum, int* boff, int nb) {
    __shared__ int s[512];
    int t = threadIdx.x;
    int v = (t < nb) ? bsum[t] : 0;
    s[t] = v;
    __syncthreads();
    for (int d = 1; d < 512; d <<= 1) {
        int x = 0;
        if (t >= d) x = s[t - d];
        __syncthreads();
        if (t >= d) s[t] += x;
        __syncthreads();
    }
    boff[t] = s[t] - v;
}

__global__ __launch_bounds__(256) void finalize_off(int* csr, int* cursor, const int* boff, int n, int etot) {
    int i = blockIdx.x * 256 + threadIdx.x;
    if (i < n) {
        int v = csr[i] + boff[i >> 9];
        csr[i] = v;
        cursor[i] = v;
    }
    if (i == 0) csr[n] = etot;
}

__global__ __launch_bounds__(256) void scatter_src(const int* ei, int* cursor, int* srcs, int E, int Etot) {
    int i = blockIdx.x * 256 + threadIdx.x;
    if (i >= Etot) return;
    int s, d;
    if (i < E) { s = ei[i]; d = ei[E + i]; }
    else       { s = i - E; d = i - E; }
    int pos = atomicAdd(&cursor[d], 1);
    srcs[pos] = s;
}

// ---------------- GEMM: [M,K] @ [K,Ncol], K%64==0, Ncol%64==0 ----------------

__global__ __launch_bounds__(256) void gemm_tile(const float* __restrict__ A, const float* __restrict__ B,
                                                 float* __restrict__ C, int M, int K, int Ncol) {
    __shared__ float As[64][68];   // transposed: As[k][m]
    __shared__ float Bs[64][68];   // Bs[k][n]
    int bm = blockIdx.x, bn = blockIdx.y;
    int t = threadIdx.x;
    int tx = t & 15, ty = t >> 4;          // 16x16 threads, 4x4 microtile
    float acc[4][4] = {{0.f}};

    for (int kt = 0; kt < K; kt += 64) {
        // A tile: 64 rows x 64 k  (store transposed)
#pragma unroll
        for (int p = 0; p < 4; ++p) {
            int id = t + p * 256;          // 1024 float4
            int row = id >> 4;
            int k4 = (id & 15) * 4;
            int g = bm * 64 + row;
            float4 v = make_float4(0.f, 0.f, 0.f, 0.f);
            if (g < M) v = *(const float4*)(A + (size_t)g * K + kt + k4);
            As[k4 + 0][row] = v.x;
            As[k4 + 1][row] = v.y;
            As[k4 + 2][row] = v.z;
            As[k4 + 3][row] = v.w;
        }
        // B tile: 64 k x 64 cols
#pragma unroll
        for (int p = 0; p < 4; ++p) {
            int id = t + p * 256;
            int kr = id >> 4;
            int c4 = (id & 15) * 4;
            float4 v = *(const float4*)(B + (size_t)(kt + kr) * Ncol + bn * 64 + c4);
            *(float4*)&Bs[kr][c4] = v;
        }
        __syncthreads();
#pragma unroll 8
        for (int k = 0; k < 64; ++k) {
            float4 a = *(float4*)&As[k][ty * 4];
            float4 b = *(float4*)&Bs[k][tx * 4];
            float av[4] = {a.x, a.y, a.z, a.w};
            float bv[4] = {b.x, b.y, b.z, b.w};
#pragma unroll
            for (int i = 0; i < 4; ++i)
#pragma unroll
                for (int j = 0; j < 4; ++j)
                    acc[i][j] += av[i] * bv[j];
        }
        __syncthreads();
    }
#pragma unroll
    for (int i = 0; i < 4; ++i) {
        int row = bm * 64 + ty * 4 + i;
        if (row < M) {
            float4 v = make_float4(acc[i][0], acc[i][1], acc[i][2], acc[i][3]);
            *(float4*)(C + (size_t)row * Ncol + bn * 64 + tx * 4) = v;
        }
    }
}

// ---------------- per-node attention logits, layer 1 (H=4, C=64) ----------------

__global__ __launch_bounds__(256) void node_alpha1(const float* __restrict__ h,
                                                   const float* __restrict__ asw, const float* __restrict__ adw,
                                                   float* __restrict__ as1, float* __restrict__ ad1, int N) {
    int idx = blockIdx.x * 256 + threadIdx.x;   // node*4 + head
    if (idx >= N * 4) return;
    int n = idx >> 2, hd = idx & 3;
    const float4* hp = (const float4*)(h + (size_t)n * 256 + hd * 64);
    const float4* sa = (const float4*)(asw + hd * 64);
    const float4* da = (const float4*)(adw + hd * 64);
    float s = 0.f, d = 0.f;
#pragma unroll
    for (int i = 0; i < 16; ++i) {
        float4 v = hp[i], a = sa[i], b = da[i];
        s += v.x * a.x + v.y * a.y + v.z * a.z + v.w * a.w;
        d += v.x * b.x + v.y * b.y + v.z * b.z + v.w * b.w;
    }
    as1[idx] = s;
    ad1[idx] = d;
}

// ---------------- layer-1 softmax + aggregate + bias + ELU -> x2 slot ----------------

__global__ __launch_bounds__(256) void agg1(const float* __restrict__ h,
                                            const float* __restrict__ as1, const float* __restrict__ ad1,
                                            const int* __restrict__ off, const int* __restrict__ srcs,
                                            const float* __restrict__ bias, float* __restrict__ x2,
                                            int N, int kofs) {
    int gw = blockIdx.x * 4 + (threadIdx.x >> 6);   // wave = (node, head)
    int lane = threadIdx.x & 63;
    if (gw >= N * 4) return;
    int n = gw >> 2, hd = gw & 3;
    int r0 = off[n], r1 = off[n + 1];
    float adn = ad1[n * 4 + hd];

    // pass A: max over in-edges (lanes split edges)
    float vmax = -1e30f;
    for (int e = r0 + lane; e < r1; e += 64) {
        int s = srcs[e];
        float v = as1[s * 4 + hd] + adn;
        vmax = fmaxf(vmax, LEAKY(v));
    }
#pragma unroll
    for (int o = 32; o > 0; o >>= 1) vmax = fmaxf(vmax, __shfl_xor(vmax, o));

    // pass B: all lanes walk edges together; lane owns channel c=lane
    float acc = 0.f, denom = 0.f;
    for (int e = r0; e < r1; ++e) {
        int s = srcs[e];
        float v = as1[s * 4 + hd] + adn;
        v = LEAKY(v);
        float p = __expf(v - vmax);
        denom += p;
        acc += p * h[(size_t)s * 256 + hd * 64 + lane];
    }
    float o = acc / (denom + 1e-16f) + bias[hd * 64 + lane];
    o = o > 0.f ? o : (__expf(o) - 1.0f);            // ELU
    x2[(size_t)n * 512 + kofs + hd * 64 + lane] = o;
}

// ---------------- layer-2 GEMM: [M,512] @ [512,16] ----------------

__global__ __launch_bounds__(256) void gemm2_k(const float* __restrict__ X, const float* __restrict__ W,
                                               float* __restrict__ H2, int M) {
    __shared__ float Ws[512 * 16];
#pragma unroll
    for (int p = 0; p < 8; ++p) {
        int id = threadIdx.x + p * 256;
        ((float4*)Ws)[id] = ((const float4*)W)[id];
    }
    __syncthreads();
    int wave = threadIdx.x >> 6, lane = threadIdx.x & 63;
    int r = lane >> 4, c = lane & 15;
    int row = blockIdx.x * 16 + wave * 4 + r;
    if (row >= M) return;
    float acc = 0.f;
    const float4* xp = (const float4*)(X + (size_t)row * 512);
#pragma unroll 4
    for (int k4 = 0; k4 < 128; ++k4) {
        float4 xv = xp[k4];
        acc += xv.x * Ws[(k4 * 4 + 0) * 16 + c];
        acc += xv.y * Ws[(k4 * 4 + 1) * 16 + c];
        acc += xv.z * Ws[(k4 * 4 + 2) * 16 + c];
        acc += xv.w * Ws[(k4 * 4 + 3) * 16 + c];
    }
    H2[(size_t)row * 16 + c] = acc;
}

__global__ __launch_bounds__(256) void node_alpha2(const float* __restrict__ h2,
                                                   const float* __restrict__ asw, const float* __restrict__ adw,
                                                   float* __restrict__ as2, float* __restrict__ ad2, int N) {
    int n = blockIdx.x * 256 + threadIdx.x;
    if (n >= N) return;
    const float4* hp = (const float4*)(h2 + (size_t)n * 16);
    const float4* sa = (const float4*)asw;
    const float4* da = (const float4*)adw;
    float s = 0.f, d = 0.f;
#pragma unroll
    for (int i = 0; i < 4; ++i) {
        float4 v = hp[i], a = sa[i], b = da[i];
        s += v.x * a.x + v.y * a.y + v.z * a.z + v.w * a.w;
        d += v.x * b.x + v.y * b.y + v.z * b.z + v.w * b.w;
    }
    as2[n] = s;
    ad2[n] = d;
}

// ---------------- layer-2 softmax + aggregate + bias -> out ----------------

__global__ __launch_bounds__(256) void agg2(const float* __restrict__ h2,
                                            const float* __restrict__ as2, const float* __restrict__ ad2,
                                            const int* __restrict__ off, const int* __restrict__ srcs,
                                            const float* __restrict__ bias2, float* __restrict__ out, int N) {
    int n = blockIdx.x * 4 + (threadIdx.x >> 6);
    int lane = threadIdx.x & 63;
    if (n >= N) return;
    int r0 = off[n], r1 = off[n + 1];
    float adn = ad2[n];

    float vmax = -1e30f;
    for (int e = r0 + lane; e < r1; e += 64) {
        int s = srcs[e];
        float v = as2[s] + adn;
        vmax = fmaxf(vmax, LEAKY(v));
    }
#pragma unroll
    for (int o = 32; o > 0; o >>= 1) vmax = fmaxf(vmax, __shfl_xor(vmax, o));

    int c = lane & 15, q = lane >> 4;   // 4 edge groups x 16 channels
    float acc = 0.f, denom = 0.f;
    for (int e = r0 + q; e < r1; e += 4) {
        int s = srcs[e];
        float v = as2[s] + adn;
        v = LEAKY(v);
        float p = __expf(v - vmax);
        denom += p;
        acc += p * h2[(size_t)s * 16 + c];
    }
    acc += __shfl_xor(acc, 16);   acc += __shfl_xor(acc, 32);
    denom += __shfl_xor(denom, 16); denom += __shfl_xor(denom, 32);
    if (lane < 16) out[(size_t)n * 16 + c] = acc / (denom + 1e-16f) + bias2[c];
}

// ---------------- launch ----------------

extern "C" void kernel_launch(void* const* d_in, const int* in_sizes, int n_in,
                              void* d_out, int out_size, void* d_ws, size_t ws_size,
                              hipStream_t stream) {
    const float* x_list = (const float*)d_in[0];   // [2, N, 128]
    const int*   ei     = (const int*)d_in[1];     // [2, E] int32
    const float* W1     = (const float*)d_in[2];   // [2, 128, 256]
    const float* as1w   = (const float*)d_in[3];   // [2, 4, 64]
    const float* ad1w   = (const float*)d_in[4];
    const float* b1     = (const float*)d_in[5];   // [2, 256]
    const float* W2     = (const float*)d_in[6];   // [512, 16]
    const float* as2w   = (const float*)d_in[7];   // [1, 16]
    const float* ad2w   = (const float*)d_in[8];
    const float* b2     = (const float*)d_in[9];   // [16]
    float* out = (float*)d_out;

    const int N = in_sizes[0] / 256;   // 50000
    const int E = in_sizes[1] / 2;     // 800000
    const int Etot = E + N;

    char* ws = (char*)d_ws;
    size_t woff = 0;
    auto alloc = [&](size_t bytes) {
        char* p = ws + woff;
        woff = (woff + bytes + 255) & ~(size_t)255;
        return p;
    };
    int*   csr    = (int*)alloc((size_t)(N + 1) * 4);
    int*   cursor = (int*)alloc((size_t)N * 4);       // doubles as deg
    int*   srcs   = (int*)alloc((size_t)Etot * 4);
    int*   bsum   = (int*)alloc(512 * 4);
    int*   boff   = (int*)alloc(512 * 4);
    float* as1    = (float*)alloc((size_t)N * 4 * 4);
    float* ad1    = (float*)alloc((size_t)N * 4 * 4);
    float* as2    = (float*)alloc((size_t)N * 4);
    float* ad2    = (float*)alloc((size_t)N * 4);
    float* h      = (float*)alloc((size_t)N * 256 * 4);   // 51.2 MB
    float* x2     = (float*)alloc((size_t)N * 512 * 4);   // 102.4 MB
    float* h2     = h;  // reuse after layer 1

    // CSR by dst
    hipMemsetAsync(cursor, 0, (size_t)N * 4, stream);
    int gE = (Etot + 255) / 256;
    count_deg<<<gE, 256, 0, stream>>>(ei, cursor, E, Etot);
    int nb = (N + 511) / 512;
    scan_block<<<nb, 512, 0, stream>>>(cursor, csr, bsum, N);
    scan_sums<<<1, 512, 0, stream>>>(bsum, boff, nb);
    finalize_off<<<(N + 255) / 256, 256, 0, stream>>>(csr, cursor, boff, N, Etot);
    scatter_src<<<gE, 256, 0, stream>>>(ei, cursor, srcs, E, Etot);

    // layer 1: two GATConvs, concat into x2
    for (int k = 0; k < 2; ++k) {
        const float* x = x_list + (size_t)k * N * 128;
        const float* W = W1 + (size_t)k * 128 * 256;
        gemm_tile<<<dim3((N + 63) / 64, 4), 256, 0, stream>>>(x, W, h, N, 128, 256);
        node_alpha1<<<(N * 4 + 255) / 256, 256, 0, stream>>>(h, as1w + k * 256, ad1w + k * 256, as1, ad1, N);
        agg1<<<N, 256, 0, stream>>>(h, as1, ad1, csr, srcs, b1 + k * 256, x2, N, k * 256);
    }

    // layer 2
    gemm2_k<<<(N + 15) / 16, 256, 0, stream>>>(x2, W2, h2, N);
    node_alpha2<<<(N + 255) / 256, 256, 0, stream>>>(h2, as2w, ad2w, as2, ad2, N);
    agg2<<<(N + 3) / 4, 256, 0, stream>>>(h2, as2, ad2, csr, srcs, b2, out, N);
}

// Round 2
// 573.250 us; speedup vs baseline: 1.7232x; 1.7232x over previous
//
#include <hip/hip_runtime.h>

#define LEAKY(v) ((v) >= 0.0f ? (v) : 0.2f * (v))

__device__ __forceinline__ unsigned short f2bf(float f) {
    unsigned int u = __float_as_uint(f);
    unsigned int r = u + 0x7FFFu + ((u >> 16) & 1u);
    return (unsigned short)(r >> 16);
}
__device__ __forceinline__ float bf2f(unsigned short u) {
    return __uint_as_float(((unsigned int)u) << 16);
}

// ---------------- CSR build ----------------

__global__ __launch_bounds__(256) void count_deg(const int* ei, int* deg, int E, int Etot) {
    int i = blockIdx.x * 256 + threadIdx.x;
    if (i >= Etot) return;
    int d = (i < E) ? ei[E + i] : (i - E);   // self-loops appended
    atomicAdd(&deg[d], 1);
}

__global__ __launch_bounds__(512) void scan_block(const int* deg, int* excl, int* bsum, int n) {
    __shared__ int s[512];
    int t = threadIdx.x;
    int i = blockIdx.x * 512 + t;
    int v = (i < n) ? deg[i] : 0;
    s[t] = v;
    __syncthreads();
    for (int d = 1; d < 512; d <<= 1) {
        int x = 0;
        if (t >= d) x = s[t - d];
        __syncthreads();
        if (t >= d) s[t] += x;
        __syncthreads();
    }
    if (i < n) excl[i] = s[t] - v;          // exclusive within block
    if (t == 511) bsum[blockIdx.x] = s[511];
}

__global__ __launch_bounds__(512) void scan_sums(const int* bsum, int* boff, int nb) {
    __shared__ int s[512];
    int t = threadIdx.x;
    int v = (t < nb) ? bsum[t] : 0;
    s[t] = v;
    __syncthreads();
    for (int d = 1; d < 512; d <<= 1) {
        int x = 0;
        if (t >= d) x = s[t - d];
        __syncthreads();
        if (t >= d) s[t] += x;
        __syncthreads();
    }
    boff[t] = s[t] - v;
}

__global__ __launch_bounds__(256) void finalize_off(int* csr, int* cursor, const int* boff, int n, int etot) {
    int i = blockIdx.x * 256 + threadIdx.x;
    if (i < n) {
        int v = csr[i] + boff[i >> 9];
        csr[i] = v;
        cursor[i] = v;
    }
    if (i == 0) csr[n] = etot;
}

__global__ __launch_bounds__(256) void scatter_src(const int* ei, int* cursor, int* srcs, int E, int Etot) {
    int i = blockIdx.x * 256 + threadIdx.x;
    if (i >= Etot) return;
    int s, d;
    if (i < E) { s = ei[i]; d = ei[E + i]; }
    else       { s = i - E; d = i - E; }
    int pos = atomicAdd(&cursor[d], 1);
    srcs[pos] = s;
}

// ---------------- GEMM: [M,128] @ [128,256] -> bf16 h ----------------

__global__ __launch_bounds__(256) void gemm_tile(const float* __restrict__ A, const float* __restrict__ B,
                                                 unsigned short* __restrict__ C, int M, int K, int Ncol) {
    __shared__ float As[64][68];   // transposed: As[k][m]
    __shared__ float Bs[64][68];   // Bs[k][n]
    int bm = blockIdx.x, bn = blockIdx.y;
    int t = threadIdx.x;
    int tx = t & 15, ty = t >> 4;          // 16x16 threads, 4x4 microtile
    float acc[4][4] = {{0.f}};

    for (int kt = 0; kt < K; kt += 64) {
#pragma unroll
        for (int p = 0; p < 4; ++p) {
            int id = t + p * 256;
            int row = id >> 4;
            int k4 = (id & 15) * 4;
            int g = bm * 64 + row;
            float4 v = make_float4(0.f, 0.f, 0.f, 0.f);
            if (g < M) v = *(const float4*)(A + (size_t)g * K + kt + k4);
            As[k4 + 0][row] = v.x;
            As[k4 + 1][row] = v.y;
            As[k4 + 2][row] = v.z;
            As[k4 + 3][row] = v.w;
        }
#pragma unroll
        for (int p = 0; p < 4; ++p) {
            int id = t + p * 256;
            int kr = id >> 4;
            int c4 = (id & 15) * 4;
            float4 v = *(const float4*)(B + (size_t)(kt + kr) * Ncol + bn * 64 + c4);
            *(float4*)&Bs[kr][c4] = v;
        }
        __syncthreads();
#pragma unroll 8
        for (int k = 0; k < 64; ++k) {
            float4 a = *(float4*)&As[k][ty * 4];
            float4 b = *(float4*)&Bs[k][tx * 4];
            float av[4] = {a.x, a.y, a.z, a.w};
            float bv[4] = {b.x, b.y, b.z, b.w};
#pragma unroll
            for (int i = 0; i < 4; ++i)
#pragma unroll
                for (int j = 0; j < 4; ++j)
                    acc[i][j] += av[i] * bv[j];
        }
        __syncthreads();
    }
#pragma unroll
    for (int i = 0; i < 4; ++i) {
        int row = bm * 64 + ty * 4 + i;
        if (row < M) {
            ushort4 v;
            v.x = f2bf(acc[i][0]); v.y = f2bf(acc[i][1]);
            v.z = f2bf(acc[i][2]); v.w = f2bf(acc[i][3]);
            *(ushort4*)(C + (size_t)row * Ncol + bn * 64 + tx * 4) = v;
        }
    }
}

// ---------------- per-node attention logits, layer 1 (H=4, C=64) ----------------

__global__ __launch_bounds__(256) void node_alpha1(const unsigned short* __restrict__ hb,
                                                   const float* __restrict__ asw, const float* __restrict__ adw,
                                                   float* __restrict__ as1, float* __restrict__ ad1, int N) {
    int idx = blockIdx.x * 256 + threadIdx.x;   // node*4 + head
    if (idx >= N * 4) return;
    int n = idx >> 2, hd = idx & 3;
    const uint4* hp = (const uint4*)(hb + (size_t)n * 256 + hd * 64);  // 8 bf16 per uint4
    const float* sa = asw + hd * 64;
    const float* da = adw + hd * 64;
    float s = 0.f, d = 0.f;
#pragma unroll
    for (int i = 0; i < 8; ++i) {
        uint4 v = hp[i];
        unsigned int w[4] = {v.x, v.y, v.z, v.w};
#pragma unroll
        for (int j = 0; j < 4; ++j) {
            float lo = __uint_as_float(w[j] << 16);
            float hi = __uint_as_float(w[j] & 0xFFFF0000u);
            int c = i * 8 + j * 2;
            s += lo * sa[c] + hi * sa[c + 1];
            d += lo * da[c] + hi * da[c + 1];
        }
    }
    as1[idx] = s;
    ad1[idx] = d;
}

// ---------------- layer-1 softmax + aggregate + bias + ELU -> x2 slot ----------------
// one wave per node, all 4 heads; lane = channel

__global__ __launch_bounds__(256) void agg1(const unsigned short* __restrict__ hb,
                                            const float* __restrict__ as1, const float* __restrict__ ad1,
                                            const int* __restrict__ off, const int* __restrict__ srcs,
                                            const float* __restrict__ bias, float* __restrict__ x2,
                                            int N, int kofs) {
    int n = blockIdx.x * 4 + (threadIdx.x >> 6);
    int lane = threadIdx.x & 63;
    if (n >= N) return;
    int r0 = off[n], r1 = off[n + 1];
    float4 adn = *(const float4*)(ad1 + (size_t)n * 4);

    // pass A: per-head max over in-edges (lanes split edges)
    float m0 = -1e30f, m1 = -1e30f, m2 = -1e30f, m3 = -1e30f;
    for (int e = r0 + lane; e < r1; e += 64) {
        int s = srcs[e];
        float4 av = *(const float4*)(as1 + (size_t)s * 4);
        m0 = fmaxf(m0, LEAKY(av.x + adn.x));
        m1 = fmaxf(m1, LEAKY(av.y + adn.y));
        m2 = fmaxf(m2, LEAKY(av.z + adn.z));
        m3 = fmaxf(m3, LEAKY(av.w + adn.w));
    }
#pragma unroll
    for (int o = 32; o > 0; o >>= 1) {
        m0 = fmaxf(m0, __shfl_xor(m0, o));
        m1 = fmaxf(m1, __shfl_xor(m1, o));
        m2 = fmaxf(m2, __shfl_xor(m2, o));
        m3 = fmaxf(m3, __shfl_xor(m3, o));
    }

    // pass B: all lanes walk edges together; lane owns channel c=lane, 4 heads
    float a0 = 0.f, a1 = 0.f, a2 = 0.f, a3 = 0.f;
    float d0 = 0.f, d1 = 0.f, d2 = 0.f, d3 = 0.f;
    for (int e = r0; e < r1; ++e) {
        int s = srcs[e];
        float4 av = *(const float4*)(as1 + (size_t)s * 4);
        const unsigned short* hp = hb + (size_t)s * 256 + lane;
        float p0 = __expf(LEAKY(av.x + adn.x) - m0);
        float p1 = __expf(LEAKY(av.y + adn.y) - m1);
        float p2 = __expf(LEAKY(av.z + adn.z) - m2);
        float p3 = __expf(LEAKY(av.w + adn.w) - m3);
        d0 += p0; d1 += p1; d2 += p2; d3 += p3;
        a0 += p0 * bf2f(hp[0]);
        a1 += p1 * bf2f(hp[64]);
        a2 += p2 * bf2f(hp[128]);
        a3 += p3 * bf2f(hp[192]);
    }

    float* xo = x2 + (size_t)n * 512 + kofs;
    float o0 = a0 / (d0 + 1e-16f) + bias[lane];
    float o1 = a1 / (d1 + 1e-16f) + bias[64 + lane];
    float o2 = a2 / (d2 + 1e-16f) + bias[128 + lane];
    float o3 = a3 / (d3 + 1e-16f) + bias[192 + lane];
    xo[lane]       = o0 > 0.f ? o0 : (__expf(o0) - 1.0f);
    xo[64 + lane]  = o1 > 0.f ? o1 : (__expf(o1) - 1.0f);
    xo[128 + lane] = o2 > 0.f ? o2 : (__expf(o2) - 1.0f);
    xo[192 + lane] = o3 > 0.f ? o3 : (__expf(o3) - 1.0f);
}

// ---------------- layer-2 GEMM: [M,512] @ [512,16] ----------------

__global__ __launch_bounds__(256) void gemm2_k(const float* __restrict__ X, const float* __restrict__ W,
                                               float* __restrict__ H2, int M) {
    __shared__ float Ws[512 * 16];
#pragma unroll
    for (int p = 0; p < 8; ++p) {
        int id = threadIdx.x + p * 256;
        ((float4*)Ws)[id] = ((const float4*)W)[id];
    }
    __syncthreads();
    int wave = threadIdx.x >> 6, lane = threadIdx.x & 63;
    int r = lane >> 4, c = lane & 15;
    int row = blockIdx.x * 16 + wave * 4 + r;
    if (row >= M) return;
    float acc = 0.f;
    const float4* xp = (const float4*)(X + (size_t)row * 512);
#pragma unroll 4
    for (int k4 = 0; k4 < 128; ++k4) {
        float4 xv = xp[k4];
        acc += xv.x * Ws[(k4 * 4 + 0) * 16 + c];
        acc += xv.y * Ws[(k4 * 4 + 1) * 16 + c];
        acc += xv.z * Ws[(k4 * 4 + 2) * 16 + c];
        acc += xv.w * Ws[(k4 * 4 + 3) * 16 + c];
    }
    H2[(size_t)row * 16 + c] = acc;
}

__global__ __launch_bounds__(256) void node_alpha2(const float* __restrict__ h2,
                                                   const float* __restrict__ asw, const float* __restrict__ adw,
                                                   float* __restrict__ as2, float* __restrict__ ad2, int N) {
    int n = blockIdx.x * 256 + threadIdx.x;
    if (n >= N) return;
    const float4* hp = (const float4*)(h2 + (size_t)n * 16);
    const float4* sa = (const float4*)asw;
    const float4* da = (const float4*)adw;
    float s = 0.f, d = 0.f;
#pragma unroll
    for (int i = 0; i < 4; ++i) {
        float4 v = hp[i], a = sa[i], b = da[i];
        s += v.x * a.x + v.y * a.y + v.z * a.z + v.w * a.w;
        d += v.x * b.x + v.y * b.y + v.z * b.z + v.w * b.w;
    }
    as2[n] = s;
    ad2[n] = d;
}

// ---------------- layer-2 softmax + aggregate + bias -> out ----------------

__global__ __launch_bounds__(256) void agg2(const float* __restrict__ h2,
                                            const float* __restrict__ as2, const float* __restrict__ ad2,
                                            const int* __restrict__ off, const int* __restrict__ srcs,
                                            const float* __restrict__ bias2, float* __restrict__ out, int N) {
    int n = blockIdx.x * 4 + (threadIdx.x >> 6);
    int lane = threadIdx.x & 63;
    if (n >= N) return;
    int r0 = off[n], r1 = off[n + 1];
    float adn = ad2[n];

    float vmax = -1e30f;
    for (int e = r0 + lane; e < r1; e += 64) {
        int s = srcs[e];
        float v = as2[s] + adn;
        vmax = fmaxf(vmax, LEAKY(v));
    }
#pragma unroll
    for (int o = 32; o > 0; o >>= 1) vmax = fmaxf(vmax, __shfl_xor(vmax, o));

    int c = lane & 15, q = lane >> 4;   // 4 edge groups x 16 channels
    float acc = 0.f, denom = 0.f;
    for (int e = r0 + q; e < r1; e += 4) {
        int s = srcs[e];
        float v = as2[s] + adn;
        v = LEAKY(v);
        float p = __expf(v - vmax);
        denom += p;
        acc += p * h2[(size_t)s * 16 + c];
    }
    acc += __shfl_xor(acc, 16);   acc += __shfl_xor(acc, 32);
    denom += __shfl_xor(denom, 16); denom += __shfl_xor(denom, 32);
    if (lane < 16) out[(size_t)n * 16 + c] = acc / (denom + 1e-16f) + bias2[c];
}

// ---------------- launch ----------------

extern "C" void kernel_launch(void* const* d_in, const int* in_sizes, int n_in,
                              void* d_out, int out_size, void* d_ws, size_t ws_size,
                              hipStream_t stream) {
    const float* x_list = (const float*)d_in[0];   // [2, N, 128]
    const int*   ei     = (const int*)d_in[1];     // [2, E] int32
    const float* W1     = (const float*)d_in[2];   // [2, 128, 256]
    const float* as1w   = (const float*)d_in[3];   // [2, 4, 64]
    const float* ad1w   = (const float*)d_in[4];
    const float* b1     = (const float*)d_in[5];   // [2, 256]
    const float* W2     = (const float*)d_in[6];   // [512, 16]
    const float* as2w   = (const float*)d_in[7];   // [1, 16]
    const float* ad2w   = (const float*)d_in[8];
    const float* b2     = (const float*)d_in[9];   // [16]
    float* out = (float*)d_out;

    const int N = in_sizes[0] / 256;   // 50000
    const int E = in_sizes[1] / 2;     // 800000
    const int Etot = E + N;

    char* ws = (char*)d_ws;
    size_t woff = 0;
    auto alloc = [&](size_t bytes) {
        char* p = ws + woff;
        woff = (woff + bytes + 255) & ~(size_t)255;
        return p;
    };
    int*   csr    = (int*)alloc((size_t)(N + 1) * 4);
    int*   cursor = (int*)alloc((size_t)N * 4);       // doubles as deg
    int*   srcs   = (int*)alloc((size_t)Etot * 4);
    int*   bsum   = (int*)alloc(512 * 4);
    int*   boff   = (int*)alloc(512 * 4);
    float* as1    = (float*)alloc((size_t)N * 4 * 4);
    float* ad1    = (float*)alloc((size_t)N * 4 * 4);
    float* as2    = (float*)alloc((size_t)N * 4);
    float* ad2    = (float*)alloc((size_t)N * 4);
    unsigned short* hb = (unsigned short*)alloc((size_t)N * 256 * 2);  // 25.6 MB bf16
    float* x2     = (float*)alloc((size_t)N * 512 * 4);   // 102.4 MB
    float* h2     = (float*)alloc((size_t)N * 16 * 4);    // 3.2 MB

    // CSR by dst
    hipMemsetAsync(cursor, 0, (size_t)N * 4, stream);
    int gE = (Etot + 255) / 256;
    count_deg<<<gE, 256, 0, stream>>>(ei, cursor, E, Etot);
    int nb = (N + 511) / 512;
    scan_block<<<nb, 512, 0, stream>>>(cursor, csr, bsum, N);
    scan_sums<<<1, 512, 0, stream>>>(bsum, boff, nb);
    finalize_off<<<(N + 255) / 256, 256, 0, stream>>>(csr, cursor, boff, N, Etot);
    scatter_src<<<gE, 256, 0, stream>>>(ei, cursor, srcs, E, Etot);

    // layer 1: two GATConvs, concat into x2
    for (int k = 0; k < 2; ++k) {
        const float* x = x_list + (size_t)k * N * 128;
        const float* W = W1 + (size_t)k * 128 * 256;
        gemm_tile<<<dim3((N + 63) / 64, 4), 256, 0, stream>>>(x, W, hb, N, 128, 256);
        node_alpha1<<<(N * 4 + 255) / 256, 256, 0, stream>>>(hb, as1w + k * 256, ad1w + k * 256, as1, ad1, N);
        agg1<<<(N + 3) / 4, 256, 0, stream>>>(hb, as1, ad1, csr, srcs, b1 + k * 256, x2, N, k * 256);
    }

    // layer 2
    gemm2_k<<<(N + 15) / 16, 256, 0, stream>>>(x2, W2, h2, N);
    node_alpha2<<<(N + 255) / 256, 256, 0, stream>>>(h2, as2w, ad2w, as2, ad2, N);
    agg2<<<(N + 3) / 4, 256, 0, stream>>>(h2, as2, ad2, csr, srcs, b2, out, N);
}

// Round 3
// 436.131 us; speedup vs baseline: 2.2650x; 1.3144x over previous
//
#include <hip/hip_runtime.h>

#define LEAKY(v) ((v) >= 0.0f ? (v) : 0.2f * (v))

__device__ __forceinline__ unsigned short f2bf(float f) {
    unsigned int u = __float_as_uint(f);
    unsigned int r = u + 0x7FFFu + ((u >> 16) & 1u);
    return (unsigned short)(r >> 16);
}
__device__ __forceinline__ float bf2f(unsigned short u) {
    return __uint_as_float(((unsigned int)u) << 16);
}

// ---------------- CSR build ----------------

__global__ __launch_bounds__(256) void count_deg(const int* ei, int* deg, int E, int Etot) {
    int i = blockIdx.x * 256 + threadIdx.x;
    if (i >= Etot) return;
    int d = (i < E) ? ei[E + i] : (i - E);   // self-loops appended
    atomicAdd(&deg[d], 1);
}

__global__ __launch_bounds__(512) void scan_block(const int* deg, int* excl, int* bsum, int n) {
    __shared__ int s[512];
    int t = threadIdx.x;
    int i = blockIdx.x * 512 + t;
    int v = (i < n) ? deg[i] : 0;
    s[t] = v;
    __syncthreads();
    for (int d = 1; d < 512; d <<= 1) {
        int x = 0;
        if (t >= d) x = s[t - d];
        __syncthreads();
        if (t >= d) s[t] += x;
        __syncthreads();
    }
    if (i < n) excl[i] = s[t] - v;
    if (t == 511) bsum[blockIdx.x] = s[511];
}

__global__ __launch_bounds__(512) void scan_sums(const int* bsum, int* boff, int nb) {
    __shared__ int s[512];
    int t = threadIdx.x;
    int v = (t < nb) ? bsum[t] : 0;
    s[t] = v;
    __syncthreads();
    for (int d = 1; d < 512; d <<= 1) {
        int x = 0;
        if (t >= d) x = s[t - d];
        __syncthreads();
        if (t >= d) s[t] += x;
        __syncthreads();
    }
    boff[t] = s[t] - v;
}

__global__ __launch_bounds__(256) void finalize_off(int* csr, int* cursor, const int* boff, int n, int etot) {
    int i = blockIdx.x * 256 + threadIdx.x;
    if (i < n) {
        int v = csr[i] + boff[i >> 9];
        csr[i] = v;
        cursor[i] = v;
    }
    if (i == 0) csr[n] = etot;
}

__global__ __launch_bounds__(256) void scatter_edge(const int* ei, int* cursor, int* srcs, int* dsts,
                                                    int E, int Etot) {
    int i = blockIdx.x * 256 + threadIdx.x;
    if (i >= Etot) return;
    int s, d;
    if (i < E) { s = ei[i]; d = ei[E + i]; }
    else       { s = i - E; d = s; }
    int pos = atomicAdd(&cursor[d], 1);
    srcs[pos] = s;
    dsts[pos] = d;
}

// ---------------- GEMM1: [M,128]@[128,256] -> bf16 h, fused alpha (head = blockIdx.y) ----------------

__global__ __launch_bounds__(256) void gemm_tile_a(const float* __restrict__ A, const float* __restrict__ B,
                                                   unsigned short* __restrict__ C,
                                                   const float* __restrict__ asw, const float* __restrict__ adw,
                                                   float* __restrict__ as_o, float* __restrict__ ad_o,
                                                   int M, int K, int Ncol) {
    __shared__ float As[64][68];   // transposed: As[k][m]
    __shared__ float Bs[64][68];   // Bs[k][n]
    int bm = blockIdx.x, bn = blockIdx.y;
    int t = threadIdx.x;
    int tx = t & 15, ty = t >> 4;
    float acc[4][4] = {{0.f}};

    for (int kt = 0; kt < K; kt += 64) {
#pragma unroll
        for (int p = 0; p < 4; ++p) {
            int id = t + p * 256;
            int row = id >> 4;
            int k4 = (id & 15) * 4;
            int g = bm * 64 + row;
            float4 v = make_float4(0.f, 0.f, 0.f, 0.f);
            if (g < M) v = *(const float4*)(A + (size_t)g * K + kt + k4);
            As[k4 + 0][row] = v.x;
            As[k4 + 1][row] = v.y;
            As[k4 + 2][row] = v.z;
            As[k4 + 3][row] = v.w;
        }
#pragma unroll
        for (int p = 0; p < 4; ++p) {
            int id = t + p * 256;
            int kr = id >> 4;
            int c4 = (id & 15) * 4;
            float4 v = *(const float4*)(B + (size_t)(kt + kr) * Ncol + bn * 64 + c4);
            *(float4*)&Bs[kr][c4] = v;
        }
        __syncthreads();
#pragma unroll 8
        for (int k = 0; k < 64; ++k) {
            float4 a = *(float4*)&As[k][ty * 4];
            float4 b = *(float4*)&Bs[k][tx * 4];
            float av[4] = {a.x, a.y, a.z, a.w};
            float bv[4] = {b.x, b.y, b.z, b.w};
#pragma unroll
            for (int i = 0; i < 4; ++i)
#pragma unroll
                for (int j = 0; j < 4; ++j)
                    acc[i][j] += av[i] * bv[j];
        }
        __syncthreads();
    }
#pragma unroll
    for (int i = 0; i < 4; ++i) {
        int row = bm * 64 + ty * 4 + i;
        bool ok = row < M;
        if (ok) {
            ushort4 v;
            v.x = f2bf(acc[i][0]); v.y = f2bf(acc[i][1]);
            v.z = f2bf(acc[i][2]); v.w = f2bf(acc[i][3]);
            *(ushort4*)(C + (size_t)row * Ncol + bn * 64 + tx * 4) = v;
        }
        // fused alpha: this block holds ALL 64 cols of head bn for these rows
        float s = 0.f, d = 0.f;
#pragma unroll
        for (int j = 0; j < 4; ++j) {
            float w = acc[i][j];
            s += w * asw[bn * 64 + tx * 4 + j];
            d += w * adw[bn * 64 + tx * 4 + j];
        }
#pragma unroll
        for (int o = 1; o < 16; o <<= 1) { s += __shfl_xor(s, o); d += __shfl_xor(d, o); }
        if (tx == 0 && ok) {
            as_o[(size_t)row * 4 + bn] = s;
            ad_o[(size_t)row * 4 + bn] = d;
        }
    }
}

// ---------------- edge-parallel softmax weights, layer 1 (both k) ----------------

__global__ __launch_bounds__(256) void edge_w1(const int* __restrict__ srcs, const int* __restrict__ dsts,
                                               const float* __restrict__ as, const float* __restrict__ ad,
                                               float* __restrict__ pw, int Etot, int N4) {
    int e = blockIdx.x * 256 + threadIdx.x;
    if (e >= Etot) return;
    int s = srcs[e], d = dsts[e];
    float4 a0 = *(const float4*)(as + (size_t)s * 4);
    float4 b0 = *(const float4*)(ad + (size_t)d * 4);
    float4 a1 = *(const float4*)(as + N4 + (size_t)s * 4);
    float4 b1 = *(const float4*)(ad + N4 + (size_t)d * 4);
    float4 p0, p1;
    p0.x = __expf(LEAKY(a0.x + b0.x));
    p0.y = __expf(LEAKY(a0.y + b0.y));
    p0.z = __expf(LEAKY(a0.z + b0.z));
    p0.w = __expf(LEAKY(a0.w + b0.w));
    p1.x = __expf(LEAKY(a1.x + b1.x));
    p1.y = __expf(LEAKY(a1.y + b1.y));
    p1.z = __expf(LEAKY(a1.z + b1.z));
    p1.w = __expf(LEAKY(a1.w + b1.w));
    *(float4*)(pw + (size_t)e * 8)     = p0;
    *(float4*)(pw + (size_t)e * 8 + 4) = p1;
}

// ---------------- layer-1 aggregate (both k) + bias + ELU -> x2 (bf16) ----------------
// one wave per node; lane = channel; 8 (k,head) pairs per lane

__global__ __launch_bounds__(256) void agg1_both(const unsigned short* __restrict__ hb,
                                                 const float* __restrict__ pw,
                                                 const int* __restrict__ off, const int* __restrict__ srcs,
                                                 const float* __restrict__ b1,
                                                 unsigned short* __restrict__ x2, int N) {
    int n = blockIdx.x * 4 + (threadIdx.x >> 6);
    int lane = threadIdx.x & 63;
    if (n >= N) return;
    int r0 = off[n], r1 = off[n + 1];
    const unsigned short* hb1 = hb + (size_t)N * 256;

    float acc[8] = {0.f, 0.f, 0.f, 0.f, 0.f, 0.f, 0.f, 0.f};
    float den[8] = {0.f, 0.f, 0.f, 0.f, 0.f, 0.f, 0.f, 0.f};
    for (int e = r0; e < r1; ++e) {
        int s = srcs[e];
        float4 p0 = *(const float4*)(pw + (size_t)e * 8);
        float4 p1 = *(const float4*)(pw + (size_t)e * 8 + 4);
        const unsigned short* h0 = hb  + (size_t)s * 256 + lane;
        const unsigned short* h1 = hb1 + (size_t)s * 256 + lane;
        den[0] += p0.x; den[1] += p0.y; den[2] += p0.z; den[3] += p0.w;
        den[4] += p1.x; den[5] += p1.y; den[6] += p1.z; den[7] += p1.w;
        acc[0] += p0.x * bf2f(h0[0]);
        acc[1] += p0.y * bf2f(h0[64]);
        acc[2] += p0.z * bf2f(h0[128]);
        acc[3] += p0.w * bf2f(h0[192]);
        acc[4] += p1.x * bf2f(h1[0]);
        acc[5] += p1.y * bf2f(h1[64]);
        acc[6] += p1.z * bf2f(h1[128]);
        acc[7] += p1.w * bf2f(h1[192]);
    }

    unsigned short* xo = x2 + (size_t)n * 512;
#pragma unroll
    for (int q = 0; q < 8; ++q) {
        float o = acc[q] / (den[q] + 1e-16f) + b1[q * 64 + lane];
        o = o > 0.f ? o : (__expf(o) - 1.0f);
        xo[q * 64 + lane] = f2bf(o);
    }
}

// ---------------- layer-2 GEMM: bf16 [M,512] @ [512,16], fused alpha2 ----------------

__global__ __launch_bounds__(256) void gemm2_k(const unsigned short* __restrict__ X2, const float* __restrict__ W,
                                               const float* __restrict__ asw, const float* __restrict__ adw,
                                               float* __restrict__ H2, float* __restrict__ as2, float* __restrict__ ad2,
                                               int M) {
    __shared__ float Ws[512 * 16];
#pragma unroll
    for (int p = 0; p < 8; ++p) {
        int id = threadIdx.x + p * 256;
        ((float4*)Ws)[id] = ((const float4*)W)[id];
    }
    __syncthreads();
    int wave = threadIdx.x >> 6, lane = threadIdx.x & 63;
    int r = lane >> 4, c = lane & 15;
    int row = blockIdx.x * 16 + wave * 4 + r;
    if (row >= M) return;
    float acc = 0.f;
    const uint4* xp = (const uint4*)(X2 + (size_t)row * 512);
#pragma unroll 4
    for (int q = 0; q < 64; ++q) {
        uint4 v = xp[q];
        unsigned int w[4] = {v.x, v.y, v.z, v.w};
#pragma unroll
        for (int j = 0; j < 4; ++j) {
            float lo = __uint_as_float(w[j] << 16);
            float hi = __uint_as_float(w[j] & 0xFFFF0000u);
            int k = q * 8 + j * 2;
            acc += lo * Ws[k * 16 + c] + hi * Ws[(k + 1) * 16 + c];
        }
    }
    H2[(size_t)row * 16 + c] = acc;
    float s = acc * asw[c], d = acc * adw[c];
#pragma unroll
    for (int o = 1; o < 16; o <<= 1) { s += __shfl_xor(s, o); d += __shfl_xor(d, o); }
    if (c == 0) { as2[row] = s; ad2[row] = d; }
}

// ---------------- edge-parallel softmax weights, layer 2 ----------------

__global__ __launch_bounds__(256) void edge_w2(const int* __restrict__ srcs, const int* __restrict__ dsts,
                                               const float* __restrict__ as2, const float* __restrict__ ad2,
                                               float* __restrict__ p2, int Etot) {
    int e = blockIdx.x * 256 + threadIdx.x;
    if (e >= Etot) return;
    float v = as2[srcs[e]] + ad2[dsts[e]];
    p2[e] = __expf(LEAKY(v));
}

// ---------------- layer-2 aggregate + bias -> out ----------------

__global__ __launch_bounds__(256) void agg2(const float* __restrict__ h2,
                                            const float* __restrict__ p2,
                                            const int* __restrict__ off, const int* __restrict__ srcs,
                                            const float* __restrict__ bias2, float* __restrict__ out, int N) {
    int n = blockIdx.x * 4 + (threadIdx.x >> 6);
    int lane = threadIdx.x & 63;
    if (n >= N) return;
    int r0 = off[n], r1 = off[n + 1];

    int c = lane & 15, q = lane >> 4;   // 4 edge groups x 16 channels
    float acc = 0.f, denom = 0.f;
    for (int e = r0 + q; e < r1; e += 4) {
        int s = srcs[e];
        float p = p2[e];
        denom += p;
        acc += p * h2[(size_t)s * 16 + c];
    }
    acc += __shfl_xor(acc, 16);     acc += __shfl_xor(acc, 32);
    denom += __shfl_xor(denom, 16); denom += __shfl_xor(denom, 32);
    if (lane < 16) out[(size_t)n * 16 + c] = acc / (denom + 1e-16f) + bias2[c];
}

// ---------------- launch ----------------

extern "C" void kernel_launch(void* const* d_in, const int* in_sizes, int n_in,
                              void* d_out, int out_size, void* d_ws, size_t ws_size,
                              hipStream_t stream) {
    const float* x_list = (const float*)d_in[0];   // [2, N, 128]
    const int*   ei     = (const int*)d_in[1];     // [2, E] int32
    const float* W1     = (const float*)d_in[2];   // [2, 128, 256]
    const float* as1w   = (const float*)d_in[3];   // [2, 4, 64]
    const float* ad1w   = (const float*)d_in[4];
    const float* b1     = (const float*)d_in[5];   // [2, 256]
    const float* W2     = (const float*)d_in[6];   // [512, 16]
    const float* as2w   = (const float*)d_in[7];   // [1, 16]
    const float* ad2w   = (const float*)d_in[8];
    const float* b2     = (const float*)d_in[9];   // [16]
    float* out = (float*)d_out;

    const int N = in_sizes[0] / 256;   // 50000
    const int E = in_sizes[1] / 2;     // 800000
    const int Etot = E + N;
    const int N4 = N * 4;

    char* ws = (char*)d_ws;
    size_t woff = 0;
    auto alloc = [&](size_t bytes) {
        char* p = ws + woff;
        woff = (woff + bytes + 255) & ~(size_t)255;
        return p;
    };
    int*   csr    = (int*)alloc((size_t)(N + 1) * 4);
    int*   cursor = (int*)alloc((size_t)N * 4);       // doubles as deg
    int*   srcs   = (int*)alloc((size_t)Etot * 4);
    int*   dsts   = (int*)alloc((size_t)Etot * 4);
    int*   bsum   = (int*)alloc(512 * 4);
    int*   boff   = (int*)alloc(512 * 4);
    float* as1    = (float*)alloc((size_t)N4 * 2 * 4);   // [2][N*4]
    float* ad1    = (float*)alloc((size_t)N4 * 2 * 4);
    float* as2    = (float*)alloc((size_t)N * 4);
    float* ad2    = (float*)alloc((size_t)N * 4);
    unsigned short* hb = (unsigned short*)alloc((size_t)N * 256 * 2 * 2);  // [2][N*256] bf16, 51.2 MB
    unsigned short* x2 = (unsigned short*)alloc((size_t)N * 512 * 2);      // bf16, 51.2 MB
    float* h2     = (float*)alloc((size_t)N * 16 * 4);    // 3.2 MB
    float* pw     = (float*)alloc((size_t)Etot * 8 * 4);  // 27.2 MB
    float* p2     = (float*)alloc((size_t)Etot * 4);      // 3.4 MB

    // CSR by dst
    hipMemsetAsync(cursor, 0, (size_t)N * 4, stream);
    int gE = (Etot + 255) / 256;
    count_deg<<<gE, 256, 0, stream>>>(ei, cursor, E, Etot);
    int nb = (N + 511) / 512;
    scan_block<<<nb, 512, 0, stream>>>(cursor, csr, bsum, N);
    scan_sums<<<1, 512, 0, stream>>>(bsum, boff, nb);
    finalize_off<<<(N + 255) / 256, 256, 0, stream>>>(csr, cursor, boff, N, Etot);
    scatter_edge<<<gE, 256, 0, stream>>>(ei, cursor, srcs, dsts, E, Etot);

    // layer 1: two GEMMs with fused alpha, then edge weights, then one merged aggregate
    for (int k = 0; k < 2; ++k) {
        const float* x = x_list + (size_t)k * N * 128;
        const float* W = W1 + (size_t)k * 128 * 256;
        gemm_tile_a<<<dim3((N + 63) / 64, 4), 256, 0, stream>>>(
            x, W, hb + (size_t)k * N * 256,
            as1w + k * 256, ad1w + k * 256,
            as1 + (size_t)k * N4, ad1 + (size_t)k * N4, N, 128, 256);
    }
    edge_w1<<<gE, 256, 0, stream>>>(srcs, dsts, as1, ad1, pw, Etot, N4);
    agg1_both<<<(N + 3) / 4, 256, 0, stream>>>(hb, pw, csr, srcs, b1, x2, N);

    // layer 2
    gemm2_k<<<(N + 15) / 16, 256, 0, stream>>>(x2, W2, as2w, ad2w, h2, as2, ad2, N);
    edge_w2<<<gE, 256, 0, stream>>>(srcs, dsts, as2, ad2, p2, Etot);
    agg2<<<(N + 3) / 4, 256, 0, stream>>>(h2, p2, csr, srcs, b2, out, N);
}

// Round 4
// 354.080 us; speedup vs baseline: 2.7898x; 1.2317x over previous
//
#include <hip/hip_runtime.h>

#define LEAKY(v) ((v) >= 0.0f ? (v) : 0.2f * (v))

typedef __attribute__((ext_vector_type(8))) short bf16x8;
typedef __attribute__((ext_vector_type(4))) float f32x4;

__device__ __forceinline__ unsigned short f2bf(float f) {
    unsigned int u = __float_as_uint(f);
    unsigned int r = u + 0x7FFFu + ((u >> 16) & 1u);
    return (unsigned short)(r >> 16);
}
__device__ __forceinline__ float bf2f(unsigned short u) {
    return __uint_as_float(((unsigned int)u) << 16);
}
__device__ __forceinline__ unsigned int pk2(float a, float b) {
    return (unsigned int)f2bf(a) | ((unsigned int)f2bf(b) << 16);
}

// ---------------- CSR build ----------------

__global__ __launch_bounds__(256) void count_deg(const int* ei, int* deg, int E, int Etot) {
    int i = blockIdx.x * 256 + threadIdx.x;
    if (i >= Etot) return;
    int d = (i < E) ? ei[E + i] : (i - E);
    atomicAdd(&deg[d], 1);
}

__global__ __launch_bounds__(512) void scan_block(const int* deg, int* excl, int* bsum, int n) {
    __shared__ int s[512];
    int t = threadIdx.x;
    int i = blockIdx.x * 512 + t;
    int v = (i < n) ? deg[i] : 0;
    s[t] = v;
    __syncthreads();
    for (int d = 1; d < 512; d <<= 1) {
        int x = 0;
        if (t >= d) x = s[t - d];
        __syncthreads();
        if (t >= d) s[t] += x;
        __syncthreads();
    }
    if (i < n) excl[i] = s[t] - v;
    if (t == 511) bsum[blockIdx.x] = s[511];
}

__global__ __launch_bounds__(512) void scan_sums(const int* bsum, int* boff, int nb) {
    __shared__ int s[512];
    int t = threadIdx.x;
    int v = (t < nb) ? bsum[t] : 0;
    s[t] = v;
    __syncthreads();
    for (int d = 1; d < 512; d <<= 1) {
        int x = 0;
        if (t >= d) x = s[t - d];
        __syncthreads();
        if (t >= d) s[t] += x;
        __syncthreads();
    }
    boff[t] = s[t] - v;
}

__global__ __launch_bounds__(256) void finalize_off(int* csr, int* cursor, const int* boff, int n, int etot) {
    int i = blockIdx.x * 256 + threadIdx.x;
    if (i < n) {
        int v = csr[i] + boff[i >> 9];
        csr[i] = v;
        cursor[i] = v;
    }
    if (i == 0) csr[n] = etot;
}

__global__ __launch_bounds__(256) void scatter_edge(const int* ei, int* cursor, int* srcs, int* dsts,
                                                    int E, int Etot) {
    int i = blockIdx.x * 256 + threadIdx.x;
    if (i >= Etot) return;
    int s, d;
    if (i < E) { s = ei[i]; d = ei[E + i]; }
    else       { s = i - E; d = s; }
    int pos = atomicAdd(&cursor[d], 1);
    srcs[pos] = s;
    dsts[pos] = d;
}

// ---------------- packing kernels ----------------

// x (f32 [nrows,128]) -> xp (bf16 [nrows,128], 16B-chunk XOR-swizzled per row)
__global__ __launch_bounds__(256) void xpack(const float* __restrict__ x, unsigned short* __restrict__ xp,
                                             int nrows) {
    int id = blockIdx.x * 256 + threadIdx.x;      // row*16 + q
    if (id >= nrows * 16) return;
    int row = id >> 4, q = id & 15;
    const float* src = x + (size_t)row * 128 + q * 8;
    float4 a = *(const float4*)src;
    float4 b = *(const float4*)(src + 4);
    uint4 v;
    v.x = pk2(a.x, a.y); v.y = pk2(a.z, a.w);
    v.z = pk2(b.x, b.y); v.w = pk2(b.z, b.w);
    *(uint4*)(xp + (size_t)row * 128 + ((q ^ (row & 7)) << 3)) = v;
}

// W1 (f32 [2][128][256]) -> wt1 (bf16 [2][256 c][128 k], transposed, swizzle baked)
__global__ __launch_bounds__(256) void wpack1(const float* __restrict__ W1, unsigned short* __restrict__ wt1) {
    int id = blockIdx.x * 256 + threadIdx.x;      // conv*4096 + c*16 + q
    if (id >= 8192) return;
    int conv = id >> 12, rem = id & 4095;
    int c = rem >> 4, q = rem & 15;
    const float* src = W1 + (size_t)conv * 32768 + (size_t)(q * 8) * 256 + c;
    float w[8];
#pragma unroll
    for (int j = 0; j < 8; ++j) w[j] = src[j * 256];
    uint4 v;
    v.x = pk2(w[0], w[1]); v.y = pk2(w[2], w[3]);
    v.z = pk2(w[4], w[5]); v.w = pk2(w[6], w[7]);
    *(uint4*)(wt1 + (size_t)conv * 32768 + c * 128 + ((q ^ (c & 7)) << 3)) = v;
}

// W2 (f32 [512][16]) -> wt2 (bf16 B-fragment image [16 steps][64 lanes][8])
__global__ __launch_bounds__(256) void wpack2(const float* __restrict__ W2, unsigned short* __restrict__ wt2) {
    int id = blockIdx.x * 256 + threadIdx.x;      // s*64 + l
    if (id >= 1024) return;
    int s = id >> 6, l = id & 63;
    const float* src = W2 + (size_t)(s * 32 + (l >> 4) * 8) * 16 + (l & 15);
    float w[8];
#pragma unroll
    for (int j = 0; j < 8; ++j) w[j] = src[j * 16];
    uint4 v;
    v.x = pk2(w[0], w[1]); v.y = pk2(w[2], w[3]);
    v.z = pk2(w[4], w[5]); v.w = pk2(w[6], w[7]);
    *(uint4*)(wt2 + (size_t)id * 8) = v;
}

// ---------------- GEMM1 MFMA: xp[conv] [N,128] @ W1[conv] -> hp packed + fused alpha ----------------
// block: 64 rows x 256 cols; 4 waves, wave w = head w (cols w*64..w*64+63)

__global__ __launch_bounds__(256) void gemm1_mfma(const unsigned short* __restrict__ xp,
                                                  const unsigned short* __restrict__ wt1,
                                                  const float* __restrict__ asw, const float* __restrict__ adw,
                                                  unsigned short* __restrict__ hp,
                                                  float* __restrict__ as1, float* __restrict__ ad1, int N) {
    __shared__ unsigned short As[64 * 128];    // 16 KB swizzled
    __shared__ unsigned short Ws[256 * 128];   // 64 KB swizzled
    int conv = blockIdx.y;
    int t = threadIdx.x;
    int w = t >> 6, l = t & 63;

    const uint4* xsrc = (const uint4*)(xp + ((size_t)conv * N + (size_t)blockIdx.x * 64) * 128);
#pragma unroll
    for (int p = 0; p < 4; ++p) {
        int id = p * 256 + t;
        int row = id >> 4;
        int grow = blockIdx.x * 64 + row;
        uint4 v = make_uint4(0, 0, 0, 0);
        if (grow < N) v = xsrc[id];
        *(uint4*)(As + (size_t)id * 8) = v;
    }
    const uint4* wsrc = (const uint4*)(wt1 + (size_t)conv * 32768);
#pragma unroll
    for (int p = 0; p < 16; ++p) {
        int id = p * 256 + t;
        *(uint4*)(Ws + (size_t)id * 8) = wsrc[id];
    }
    __syncthreads();

    f32x4 acc[4][4];
#pragma unroll
    for (int mt = 0; mt < 4; ++mt)
#pragma unroll
        for (int nt = 0; nt < 4; ++nt) acc[mt][nt] = (f32x4){0.f, 0.f, 0.f, 0.f};

    int lr = l & 15, lg = l >> 4;
#pragma unroll
    for (int s = 0; s < 4; ++s) {
        int kq = s * 4 + lg;
        bf16x8 af[4], bf[4];
#pragma unroll
        for (int mt = 0; mt < 4; ++mt) {
            int r = mt * 16 + lr;
            af[mt] = *(const bf16x8*)(As + r * 128 + ((kq ^ (r & 7)) << 3));
        }
#pragma unroll
        for (int nt = 0; nt < 4; ++nt) {
            int c = w * 64 + nt * 16 + lr;
            bf[nt] = *(const bf16x8*)(Ws + c * 128 + ((kq ^ (c & 7)) << 3));
        }
#pragma unroll
        for (int mt = 0; mt < 4; ++mt)
#pragma unroll
            for (int nt = 0; nt < 4; ++nt)
                acc[mt][nt] = __builtin_amdgcn_mfma_f32_16x16x32_bf16(af[mt], bf[nt], acc[mt][nt], 0, 0, 0);
    }

    // epilogue: hp[n*512 + c*8 + conv*4 + head], alpha per row
    float aswv[4], adwv[4];
#pragma unroll
    for (int nt = 0; nt < 4; ++nt) {
        aswv[nt] = asw[conv * 256 + w * 64 + nt * 16 + lr];
        adwv[nt] = adw[conv * 256 + w * 64 + nt * 16 + lr];
    }
#pragma unroll
    for (int mt = 0; mt < 4; ++mt) {
#pragma unroll
        for (int i = 0; i < 4; ++i) {
            int grow = blockIdx.x * 64 + mt * 16 + lg * 4 + i;
            bool ok = grow < N;
            float sv = 0.f, dv = 0.f;
#pragma unroll
            for (int nt = 0; nt < 4; ++nt) {
                float hv = acc[mt][nt][i];
                if (ok) hp[(size_t)grow * 512 + (nt * 16 + lr) * 8 + conv * 4 + w] = f2bf(hv);
                sv += hv * aswv[nt];
                dv += hv * adwv[nt];
            }
#pragma unroll
            for (int o = 1; o < 16; o <<= 1) {
                sv += __shfl_xor(sv, o);
                dv += __shfl_xor(dv, o);
            }
            if (lr == 0 && ok) {
                as1[(size_t)conv * N * 4 + (size_t)grow * 4 + w] = sv;
                ad1[(size_t)conv * N * 4 + (size_t)grow * 4 + w] = dv;
            }
        }
    }
}

// ---------------- edge-parallel softmax weights, layer 1 (both convs) ----------------

__global__ __launch_bounds__(256) void edge_w1(const int* __restrict__ srcs, const int* __restrict__ dsts,
                                               const float* __restrict__ as, const float* __restrict__ ad,
                                               float* __restrict__ pw, int Etot, int N4) {
    int e = blockIdx.x * 256 + threadIdx.x;
    if (e >= Etot) return;
    int s = srcs[e], d = dsts[e];
    float4 a0 = *(const float4*)(as + (size_t)s * 4);
    float4 b0 = *(const float4*)(ad + (size_t)d * 4);
    float4 a1 = *(const float4*)(as + N4 + (size_t)s * 4);
    float4 b1 = *(const float4*)(ad + N4 + (size_t)d * 4);
    float4 p0, p1;
    p0.x = __expf(LEAKY(a0.x + b0.x));
    p0.y = __expf(LEAKY(a0.y + b0.y));
    p0.z = __expf(LEAKY(a0.z + b0.z));
    p0.w = __expf(LEAKY(a0.w + b0.w));
    p1.x = __expf(LEAKY(a1.x + b1.x));
    p1.y = __expf(LEAKY(a1.y + b1.y));
    p1.z = __expf(LEAKY(a1.z + b1.z));
    p1.w = __expf(LEAKY(a1.w + b1.w));
    *(float4*)(pw + (size_t)e * 8)     = p0;
    *(float4*)(pw + (size_t)e * 8 + 4) = p1;
}

// ---------------- layer-1 aggregate: packed 16B gather, shfl-broadcast srcs ----------------

#define ACC8(g, pa, pb) {                                                      \
    float h0 = __uint_as_float((g).x << 16), h1 = __uint_as_float((g).x & 0xFFFF0000u); \
    float h2v = __uint_as_float((g).y << 16), h3 = __uint_as_float((g).y & 0xFFFF0000u); \
    float h4 = __uint_as_float((g).z << 16), h5 = __uint_as_float((g).z & 0xFFFF0000u); \
    float h6 = __uint_as_float((g).w << 16), h7 = __uint_as_float((g).w & 0xFFFF0000u); \
    den[0] += (pa).x; acc[0] += (pa).x * h0;                                   \
    den[1] += (pa).y; acc[1] += (pa).y * h1;                                   \
    den[2] += (pa).z; acc[2] += (pa).z * h2v;                                  \
    den[3] += (pa).w; acc[3] += (pa).w * h3;                                   \
    den[4] += (pb).x; acc[4] += (pb).x * h4;                                   \
    den[5] += (pb).y; acc[5] += (pb).y * h5;                                   \
    den[6] += (pb).z; acc[6] += (pb).z * h6;                                   \
    den[7] += (pb).w; acc[7] += (pb).w * h7; }

__global__ __launch_bounds__(256) void agg1_both(const unsigned short* __restrict__ hp,
                                                 const float* __restrict__ pw,
                                                 const int* __restrict__ off, const int* __restrict__ srcs,
                                                 const float* __restrict__ b1,
                                                 unsigned short* __restrict__ x2, int N) {
    int n = blockIdx.x * 4 + (threadIdx.x >> 6);
    int lane = threadIdx.x & 63;
    if (n >= N) return;
    int r0 = off[n], r1 = off[n + 1];

    float acc[8] = {0.f, 0.f, 0.f, 0.f, 0.f, 0.f, 0.f, 0.f};
    float den[8] = {0.f, 0.f, 0.f, 0.f, 0.f, 0.f, 0.f, 0.f};

    for (int base = r0; base < r1; base += 64) {
        int cnt = min(64, r1 - base);
        int my = (base + lane < r1) ? srcs[base + lane] : 0;
        int j = 0;
        for (; j + 2 <= cnt; j += 2) {
            int s0 = __shfl(my, j);
            int s1 = __shfl(my, j + 1);
            uint4 g0 = *(const uint4*)(hp + (size_t)s0 * 512 + lane * 8);
            uint4 g1 = *(const uint4*)(hp + (size_t)s1 * 512 + lane * 8);
            float4 pa0 = *(const float4*)(pw + (size_t)(base + j) * 8);
            float4 pb0 = *(const float4*)(pw + (size_t)(base + j) * 8 + 4);
            float4 pa1 = *(const float4*)(pw + (size_t)(base + j + 1) * 8);
            float4 pb1 = *(const float4*)(pw + (size_t)(base + j + 1) * 8 + 4);
            ACC8(g0, pa0, pb0);
            ACC8(g1, pa1, pb1);
        }
        if (j < cnt) {
            int s0 = __shfl(my, j);
            uint4 g0 = *(const uint4*)(hp + (size_t)s0 * 512 + lane * 8);
            float4 pa0 = *(const float4*)(pw + (size_t)(base + j) * 8);
            float4 pb0 = *(const float4*)(pw + (size_t)(base + j) * 8 + 4);
            ACC8(g0, pa0, pb0);
        }
    }

    unsigned short* xo = x2 + (size_t)n * 512;
#pragma unroll
    for (int q = 0; q < 8; ++q) {
        int k = q >> 2, hd = q & 3;
        int ofs = k * 256 + hd * 64 + lane;
        float o = acc[q] / (den[q] + 1e-16f) + b1[ofs];
        o = o > 0.f ? o : (__expf(o) - 1.0f);
        xo[ofs] = f2bf(o);
    }
}

// ---------------- GEMM2 MFMA: x2 [N,512] @ wt2 -> h2 [N,16] + fused alpha2 ----------------

__global__ __launch_bounds__(256) void gemm2_mfma(const unsigned short* __restrict__ x2,
                                                  const unsigned short* __restrict__ wt2,
                                                  const float* __restrict__ asw2, const float* __restrict__ adw2,
                                                  float* __restrict__ h2,
                                                  float* __restrict__ as2, float* __restrict__ ad2, int N) {
    int t = threadIdx.x;
    int w = t >> 6, l = t & 63;
    int rowbase = (blockIdx.x * 4 + w) * 16;
    if (rowbase >= N) return;
    int lr = l & 15, lg = l >> 4;

    f32x4 acc = (f32x4){0.f, 0.f, 0.f, 0.f};
    const unsigned short* ap = x2 + (size_t)(rowbase + lr) * 512 + lg * 8;
#pragma unroll
    for (int s = 0; s < 16; ++s) {
        bf16x8 av = *(const bf16x8*)(ap + s * 32);
        bf16x8 bv = *(const bf16x8*)(wt2 + ((size_t)s * 64 + l) * 8);
        acc = __builtin_amdgcn_mfma_f32_16x16x32_bf16(av, bv, acc, 0, 0, 0);
    }

    float asv = asw2[lr], adv = adw2[lr];
#pragma unroll
    for (int i = 0; i < 4; ++i) {
        int row = rowbase + lg * 4 + i;
        if (row < N) h2[(size_t)row * 16 + lr] = acc[i];
        float sv = acc[i] * asv, dv = acc[i] * adv;
#pragma unroll
        for (int o = 1; o < 16; o <<= 1) {
            sv += __shfl_xor(sv, o);
            dv += __shfl_xor(dv, o);
        }
        if (lr == 0 && row < N) { as2[row] = sv; ad2[row] = dv; }
    }
}

// ---------------- edge-parallel softmax weights, layer 2 ----------------

__global__ __launch_bounds__(256) void edge_w2(const int* __restrict__ srcs, const int* __restrict__ dsts,
                                               const float* __restrict__ as2, const float* __restrict__ ad2,
                                               float* __restrict__ p2, int Etot) {
    int e = blockIdx.x * 256 + threadIdx.x;
    if (e >= Etot) return;
    float v = as2[srcs[e]] + ad2[dsts[e]];
    p2[e] = __expf(LEAKY(v));
}

// ---------------- layer-2 aggregate + bias -> out ----------------

__global__ __launch_bounds__(256) void agg2(const float* __restrict__ h2,
                                            const float* __restrict__ p2,
                                            const int* __restrict__ off, const int* __restrict__ srcs,
                                            const float* __restrict__ bias2, float* __restrict__ out, int N) {
    int n = blockIdx.x * 4 + (threadIdx.x >> 6);
    int lane = threadIdx.x & 63;
    if (n >= N) return;
    int r0 = off[n], r1 = off[n + 1];

    int c = lane & 15, q = lane >> 4;
    float acc = 0.f, denom = 0.f;
    for (int e = r0 + q; e < r1; e += 4) {
        int s = srcs[e];
        float p = p2[e];
        denom += p;
        acc += p * h2[(size_t)s * 16 + c];
    }
    acc += __shfl_xor(acc, 16);     acc += __shfl_xor(acc, 32);
    denom += __shfl_xor(denom, 16); denom += __shfl_xor(denom, 32);
    if (lane < 16) out[(size_t)n * 16 + c] = acc / (denom + 1e-16f) + bias2[c];
}

// ---------------- launch ----------------

extern "C" void kernel_launch(void* const* d_in, const int* in_sizes, int n_in,
                              void* d_out, int out_size, void* d_ws, size_t ws_size,
                              hipStream_t stream) {
    const float* x_list = (const float*)d_in[0];   // [2, N, 128]
    const int*   ei     = (const int*)d_in[1];     // [2, E] int32
    const float* W1     = (const float*)d_in[2];   // [2, 128, 256]
    const float* as1w   = (const float*)d_in[3];   // [2, 4, 64]
    const float* ad1w   = (const float*)d_in[4];
    const float* b1     = (const float*)d_in[5];   // [2, 256]
    const float* W2     = (const float*)d_in[6];   // [512, 16]
    const float* as2w   = (const float*)d_in[7];
    const float* ad2w   = (const float*)d_in[8];
    const float* b2     = (const float*)d_in[9];   // [16]
    float* out = (float*)d_out;

    const int N = in_sizes[0] / 256;   // 50000
    const int E = in_sizes[1] / 2;     // 800000
    const int Etot = E + N;
    const int N4 = N * 4;

    char* ws = (char*)d_ws;
    size_t woff = 0;
    auto alloc = [&](size_t bytes) {
        char* p = ws + woff;
        woff = (woff + bytes + 255) & ~(size_t)255;
        return p;
    };
    int*   csr    = (int*)alloc((size_t)(N + 1) * 4);
    int*   cursor = (int*)alloc((size_t)N * 4);
    int*   srcs   = (int*)alloc((size_t)Etot * 4);
    int*   dsts   = (int*)alloc((size_t)Etot * 4);
    int*   bsum   = (int*)alloc(512 * 4);
    int*   boff   = (int*)alloc(512 * 4);
    float* as1    = (float*)alloc((size_t)N4 * 2 * 4);   // [2][N*4]
    float* ad1    = (float*)alloc((size_t)N4 * 2 * 4);
    float* as2    = (float*)alloc((size_t)N * 4);
    float* ad2    = (float*)alloc((size_t)N * 4);
    unsigned short* xp  = (unsigned short*)alloc((size_t)N * 128 * 2 * 2);  // [2][N][128] bf16
    unsigned short* wt1 = (unsigned short*)alloc(2 * 32768 * 2);
    unsigned short* wt2 = (unsigned short*)alloc(16 * 64 * 8 * 2);
    unsigned short* hp  = (unsigned short*)alloc((size_t)N * 512 * 2);      // packed h, 51.2 MB
    unsigned short* x2  = (unsigned short*)alloc((size_t)N * 512 * 2);      // bf16, 51.2 MB
    float* h2     = (float*)alloc((size_t)N * 16 * 4);
    float* pw     = (float*)alloc((size_t)Etot * 8 * 4);
    float* p2     = (float*)alloc((size_t)Etot * 4);

    // CSR by dst
    hipMemsetAsync(cursor, 0, (size_t)N * 4, stream);
    int gE = (Etot + 255) / 256;
    count_deg<<<gE, 256, 0, stream>>>(ei, cursor, E, Etot);
    int nb = (N + 511) / 512;
    scan_block<<<nb, 512, 0, stream>>>(cursor, csr, bsum, N);
    scan_sums<<<1, 512, 0, stream>>>(bsum, boff, nb);
    finalize_off<<<(N + 255) / 256, 256, 0, stream>>>(csr, cursor, boff, N, Etot);
    scatter_edge<<<gE, 256, 0, stream>>>(ei, cursor, srcs, dsts, E, Etot);

    // packing (per-conv xpack so swizzle uses conv-local row)
    for (int k = 0; k < 2; ++k)
        xpack<<<(N * 16 + 255) / 256, 256, 0, stream>>>(x_list + (size_t)k * N * 128,
                                                        xp + (size_t)k * N * 128, N);
    wpack1<<<32, 256, 0, stream>>>(W1, wt1);
    wpack2<<<4, 256, 0, stream>>>(W2, wt2);

    // layer 1
    gemm1_mfma<<<dim3((N + 63) / 64, 2), 256, 0, stream>>>(xp, wt1, as1w, ad1w, hp, as1, ad1, N);
    edge_w1<<<gE, 256, 0, stream>>>(srcs, dsts, as1, ad1, pw, Etot, N4);
    agg1_both<<<(N + 3) / 4, 256, 0, stream>>>(hp, pw, csr, srcs, b1, x2, N);

    // layer 2
    gemm2_mfma<<<(N + 63) / 64, 256, 0, stream>>>(x2, wt2, as2w, ad2w, h2, as2, ad2, N);
    edge_w2<<<gE, 256, 0, stream>>>(srcs, dsts, as2, ad2, p2, Etot);
    agg2<<<(N + 3) / 4, 256, 0, stream>>>(h2, p2, csr, srcs, b2, out, N);
}